// Round 2
// baseline (121.597 us; speedup 1.0000x reference)
//
#include <hip/hip_runtime.h>
#include <math.h>

#define NPTS 16384
#define NSMP_TOT 8192      // 8 * 1024
#define TILE 1024
#define KNN 10
#define QPW 4              // queries per wave

__global__ __launch_bounds__(256) void softproj_kernel(
    const float* __restrict__ xyz,
    const float* __restrict__ sxyz,
    const float* __restrict__ temp,
    float* __restrict__ out)
{
    // point p stored at slot (p&3)*256 + (p>>2): conflict-free b128 writes AND reads
    __shared__ float4 tile4[TILE];
    const int lane = threadIdx.x & 63;
    const int wid  = threadIdx.x >> 6;
    const int qbase = (blockIdx.x * 4 + wid) * QPW;   // first of 4 query ids
    const int b = qbase >> 10;                         // batch (16 queries never straddle)

    const float* batch_xyz = xyz + (size_t)b * NPTS * 3;

    // load 4 queries, premultiply by -2 for the d' = p2 - 2 p.q form
    float nqx[QPW], nqy[QPW], nqz[QPW];
    #pragma unroll
    for (int q = 0; q < QPW; ++q) {
        const float* s = sxyz + (size_t)(qbase + q) * 3;
        nqx[q] = -2.f * s[0]; nqy[q] = -2.f * s[1]; nqz[q] = -2.f * s[2];
    }

    // Wave-cooperative sorted top-K per query: lane j<10 holds j-th smallest (d', idx)
    float kd[QPW]; int ki[QPW]; float th[QPW];
    #pragma unroll
    for (int q = 0; q < QPW; ++q) { kd[q] = INFINITY; ki[q] = 0; th[q] = INFINITY; }

    for (int tile = 0; tile < NPTS / TILE; ++tile) {
        __syncthreads();
        // stage: thread t loads points 4t..4t+3 (three float4s = 48B contiguous),
        // computes |p|^2, writes transposed slots t, 256+t, 512+t, 768+t
        {
            const float4* src = (const float4*)(batch_xyz + (size_t)tile * TILE * 3);
            const int t3 = threadIdx.x * 3;
            const float4 a = src[t3 + 0];
            const float4 bb = src[t3 + 1];
            const float4 c = src[t3 + 2];
            const int t = threadIdx.x;
            tile4[0 * 256 + t] = make_float4(a.x, a.y, a.z,  fmaf(a.x,a.x, fmaf(a.y,a.y, a.z*a.z)));
            tile4[1 * 256 + t] = make_float4(a.w, bb.x, bb.y, fmaf(a.w,a.w, fmaf(bb.x,bb.x, bb.y*bb.y)));
            tile4[2 * 256 + t] = make_float4(bb.z, bb.w, c.x, fmaf(bb.z,bb.z, fmaf(bb.w,bb.w, c.x*c.x)));
            tile4[3 * 256 + t] = make_float4(c.y, c.z, c.w,  fmaf(c.y,c.y, fmaf(c.z,c.z, c.w*c.w)));
        }
        __syncthreads();

        #pragma unroll 4
        for (int j = 0; j < TILE / 64; ++j) {
            const float4 pv = tile4[j * 64 + lane];            // one ds_read_b128
            // slot -> point index: p = (j&3)*256 + lane*4 + (j>>2)
            const int pidx = tile * TILE + (j & 3) * 256 + lane * 4 + (j >> 2);
            #pragma unroll
            for (int q = 0; q < QPW; ++q) {
                const float d = fmaf(pv.x, nqx[q], fmaf(pv.y, nqy[q], fmaf(pv.z, nqz[q], pv.w)));
                unsigned long long mask = __ballot(d < th[q]);
                while (mask) {                                  // rare after warm-up
                    const int w = __builtin_ctzll(mask);
                    mask &= mask - 1;
                    const float v  = __shfl(d, w);
                    const int   vi = __shfl(pidx, w);
                    if (v < th[q]) {                            // re-check vs updated threshold
                        const unsigned long long sm = __ballot(kd[q] < v);
                        const int pos = __popcll(sm);
                        const float ud = __shfl_up(kd[q], 1);
                        const int   ui = __shfl_up(ki[q], 1);
                        if (lane < KNN && lane >= pos) {
                            kd[q] = (lane == pos) ? v  : ud;
                            ki[q] = (lane == pos) ? vi : ui;
                        }
                        th[q] = __shfl(kd[q], KNN - 1);
                    }
                }
            }
        }
    }

    // ---- epilogue: reconstruct d2 = max(d' + |q|^2, 0), softmax, weighted sum ----
    const float t = temp[0];
    const float invt2 = 1.0f / (t * t);
    #pragma unroll
    for (int q = 0; q < QPW; ++q) {
        const int gid = qbase + q;
        const float* s = sxyz + (size_t)gid * 3;
        const float q2 = fmaf(s[0],s[0], fmaf(s[1],s[1], s[2]*s[2]));
        const float d2 = fmaxf(kd[q] + q2, 0.0f);    // clamp is monotone: order preserved
        const float dmin = __shfl(d2, 0);            // lane 0 holds the smallest
        float w = 0.f, px = 0.f, py = 0.f, pz = 0.f;
        if (lane < KNN) {
            w = __expf((dmin - d2) * invt2);
            const float* pp = batch_xyz + (size_t)ki[q] * 3;
            px = pp[0]; py = pp[1]; pz = pp[2];
        }
        float sw = w, sx = w * px, sy = w * py, sz = w * pz;
        #pragma unroll
        for (int off = 8; off >= 1; off >>= 1) {
            sw += __shfl_xor(sw, off);
            sx += __shfl_xor(sx, off);
            sy += __shfl_xor(sy, off);
            sz += __shfl_xor(sz, off);
        }
        if (lane == 0) {
            const float inv = 1.0f / sw;
            out[(size_t)gid * 3 + 0] = sx * inv;
            out[(size_t)gid * 3 + 1] = sy * inv;
            out[(size_t)gid * 3 + 2] = sz * inv;
        }
    }
    if (qbase == 0 && lane == 0) out[NSMP_TOT * 3] = t;   // tuple output 2: temp
}

extern "C" void kernel_launch(void* const* d_in, const int* in_sizes, int n_in,
                              void* d_out, int out_size, void* d_ws, size_t ws_size,
                              hipStream_t stream) {
    const float* xyz  = (const float*)d_in[0];   // [8,16384,3]
    const float* sxyz = (const float*)d_in[1];   // [8,1024,3]
    const float* temp = (const float*)d_in[2];   // scalar
    float* out = (float*)d_out;                  // 8*1024*3 + 1 floats

    dim3 grid(NSMP_TOT / (4 * QPW));   // 4 waves/block * 4 queries/wave = 16 queries/block
    dim3 block(256);
    hipLaunchKernelGGL(softproj_kernel, grid, block, 0, stream, xyz, sxyz, temp, out);
}